// Round 1
// baseline (67.289 us; speedup 1.0000x reference)
//
#include <hip/hip_runtime.h>

typedef float f4 __attribute__((ext_vector_type(4)));

#define NEG_INF -1e9f

// ---------------------------------------------------------------------------
// Kernel 1: dual projection GEMM + exp epilogue.
//   z=0: EQ[r][u]     = exp(2 * (query @ W1)[r][u])   rows r = b*TQ+tq (1024)
//   z=1: EKT[b][u][v] = exp(2 * (value @ W2)[b*TV+v][u])  (transposed store)
// 64x64 tile, BK=32, 256 threads, 4x4 micro-tile, f32 SIMT.
// ---------------------------------------------------------------------------
__global__ __launch_bounds__(256) void bah_proj(
    const float* __restrict__ query, const float* __restrict__ value,
    const float* __restrict__ W1, const float* __restrict__ W2,
    float* __restrict__ EQ, float* __restrict__ EKT)
{
  const int z  = blockIdx.z;
  const int c0 = blockIdx.x * 64;
  const int r0 = blockIdx.y * 64;
  const float* __restrict__ X = z ? value : query;
  const float* __restrict__ W = z ? W2 : W1;

  __shared__ float As[32][68];   // [k][row], padded: conflict-light, 16B-aligned rows
  __shared__ float Bs[32][68];   // [k][col]

  const int tid = threadIdx.x;
  const int tx = tid & 15;
  const int ty = tid >> 4;

  float acc[4][4] = {};

  for (int kb = 0; kb < 512; kb += 32) {
#pragma unroll
    for (int t = 0; t < 2; ++t) {
      const int id  = t * 256 + tid;
      const int ar  = id >> 3;
      const int akc = (id & 7) * 4;
      f4 av = *reinterpret_cast<const f4*>(&X[(r0 + ar) * 512 + kb + akc]);
      As[akc + 0][ar] = av[0];
      As[akc + 1][ar] = av[1];
      As[akc + 2][ar] = av[2];
      As[akc + 3][ar] = av[3];
      const int bkk = id >> 4;
      const int bcc = (id & 15) * 4;
      f4 wv = *reinterpret_cast<const f4*>(&W[(kb + bkk) * 512 + c0 + bcc]);
      *reinterpret_cast<f4*>(&Bs[bkk][bcc]) = wv;
    }
    __syncthreads();
#pragma unroll
    for (int kk = 0; kk < 32; ++kk) {
      f4 a  = *reinterpret_cast<const f4*>(&As[kk][ty * 4]);
      f4 bb = *reinterpret_cast<const f4*>(&Bs[kk][tx * 4]);
#pragma unroll
      for (int i = 0; i < 4; ++i)
#pragma unroll
        for (int j = 0; j < 4; ++j)
          acc[i][j] = fmaf(a[i], bb[j], acc[i][j]);
    }
    __syncthreads();
  }

#pragma unroll
  for (int i = 0; i < 4; ++i) {
    const int r = r0 + ty * 4 + i;
#pragma unroll
    for (int j = 0; j < 4; ++j) {
      const int c = c0 + tx * 4 + j;
      const float e = __expf(2.0f * acc[i][j]);
      if (z == 0) EQ[r * 512 + c] = e;
      else        EKT[(r >> 8) * (512 * 256) + c * 256 + (r & 255)] = e;
    }
  }
}

// ---------------------------------------------------------------------------
// Kernel 2: fused scores + masked softmax + context.
// Grid: 256 blocks = (b, tq-group of 4). 512 threads = 8 waves.
// Threads: v = tid&255, u-half h = tid>>8 (each half does 256 u's).
// Per element: tanh(q+k) = 1 - 2/(EQ*EK + 1)  -> fma, rcp, fma, fma.
// ---------------------------------------------------------------------------
__global__ __launch_bounds__(512) void bah_attn(
    const float* __restrict__ EQ, const float* __restrict__ EKT,
    const float* __restrict__ value, const int* __restrict__ mask,
    const float* __restrict__ scale,
    float* __restrict__ ctx_out, float* __restrict__ attn_out)
{
  const int blk = blockIdx.x;
  const int b   = blk >> 6;
  const int tq0 = (blk & 63) * 4;
  const int bq  = b * 256 + tq0;

  const int tid = threadIdx.x;
  const int v   = tid & 255;
  const int w   = tid >> 6;
  const int l   = tid & 63;
  const int hs  = __builtin_amdgcn_readfirstlane(tid >> 8); // wave-uniform u-half

  __shared__ float part[2][4][256];
  __shared__ float wred[4][8];
  __shared__ float atT[256][4];
  __shared__ float ctxp[4][4][512];

  const float* __restrict__ ekb = EKT + b * (512 * 256);
  const float* __restrict__ eqb = EQ + bq * 512;

  float accr[4] = {0.f, 0.f, 0.f, 0.f};

#pragma unroll 4
  for (int uu = 0; uu < 256; ++uu) {
    const int u = hs * 256 + uu;
    const float ek = ekb[u * 256 + v];      // coalesced: lane = v
    const float s  = scale[u];              // uniform
    const float e0 = eqb[u];                // uniform
    const float e1 = eqb[512 + u];
    const float e2 = eqb[1024 + u];
    const float e3 = eqb[1536 + u];
    const float r0_ = __builtin_amdgcn_rcpf(fmaf(e0, ek, 1.0f));
    const float r1_ = __builtin_amdgcn_rcpf(fmaf(e1, ek, 1.0f));
    const float r2_ = __builtin_amdgcn_rcpf(fmaf(e2, ek, 1.0f));
    const float r3_ = __builtin_amdgcn_rcpf(fmaf(e3, ek, 1.0f));
    accr[0] = fmaf(s, fmaf(r0_, -2.0f, 1.0f), accr[0]);
    accr[1] = fmaf(s, fmaf(r1_, -2.0f, 1.0f), accr[1]);
    accr[2] = fmaf(s, fmaf(r2_, -2.0f, 1.0f), accr[2]);
    accr[3] = fmaf(s, fmaf(r3_, -2.0f, 1.0f), accr[3]);
  }

#pragma unroll
  for (int i = 0; i < 4; ++i) part[hs][i][v] = accr[i];
  __syncthreads();

  float sc[4], ex[4];
  if (tid < 256) {
#pragma unroll
    for (int i = 0; i < 4; ++i) sc[i] = part[0][i][v] + part[1][i][v];
    const bool mok = (mask[b * 256 + v] != 0);
#pragma unroll
    for (int i = 0; i < 4; ++i) {
      sc[i] = mok ? sc[i] : NEG_INF;
      float m = sc[i];
#pragma unroll
      for (int off = 32; off; off >>= 1) m = fmaxf(m, __shfl_xor(m, off));
      if (l == 0) wred[i][w] = m;
    }
  }
  __syncthreads();
  if (tid < 256) {
#pragma unroll
    for (int i = 0; i < 4; ++i) {
      const float m = fmaxf(fmaxf(wred[i][0], wred[i][1]),
                            fmaxf(wred[i][2], wred[i][3]));
      float e = __expf(sc[i] - m);
      ex[i] = e;
      float sm = e;
#pragma unroll
      for (int off = 32; off; off >>= 1) sm += __shfl_xor(sm, off);
      if (l == 0) wred[i][4 + w] = sm;
    }
  }
  __syncthreads();
  if (tid < 256) {
#pragma unroll
    for (int i = 0; i < 4; ++i) {
      const float denom = (wred[i][4] + wred[i][5]) + (wred[i][6] + wred[i][7]);
      const float a = ex[i] * __builtin_amdgcn_rcpf(denom);
      atT[v][i] = a;
      attn_out[(bq + i) * 256 + v] = a;   // coalesced
    }
  }
  __syncthreads();

  // context: wave w owns v-range (w&3)*64, d-half (w>>2); partials in LDS.
  const int vr = (w & 3) * 64;
  const int dh = (w >> 2) * 256;
  const float* __restrict__ vb = value + b * (256 * 512);
  f4 c[4] = {};
  for (int v2 = 0; v2 < 64; ++v2) {
    const f4 a4 = *reinterpret_cast<const f4*>(&atT[vr + v2][0]);   // broadcast
    const f4 vv = *reinterpret_cast<const f4*>(&vb[(vr + v2) * 512 + dh + l * 4]);
#pragma unroll
    for (int i = 0; i < 4; ++i) c[i] += a4[i] * vv;
  }
#pragma unroll
  for (int i = 0; i < 4; ++i)
    *reinterpret_cast<f4*>(&ctxp[w & 3][i][dh + l * 4]) = c[i];
  __syncthreads();

  {
    const int i  = tid >> 7;
    const int d4 = (tid & 127) * 4;
    const f4 s0 = *reinterpret_cast<const f4*>(&ctxp[0][i][d4]);
    const f4 s1 = *reinterpret_cast<const f4*>(&ctxp[1][i][d4]);
    const f4 s2 = *reinterpret_cast<const f4*>(&ctxp[2][i][d4]);
    const f4 s3 = *reinterpret_cast<const f4*>(&ctxp[3][i][d4]);
    const f4 r = (s0 + s1) + (s2 + s3);
    *reinterpret_cast<f4*>(&ctx_out[(bq + i) * 512 + d4]) = r;
  }
}

// ---------------------------------------------------------------------------
extern "C" void kernel_launch(void* const* d_in, const int* in_sizes, int n_in,
                              void* d_out, int out_size, void* d_ws, size_t ws_size,
                              hipStream_t stream) {
  const float* query = (const float*)d_in[0];
  const float* value = (const float*)d_in[1];
  const int*   mask  = (const int*)d_in[2];
  const float* W1    = (const float*)d_in[3];
  const float* W2    = (const float*)d_in[4];
  const float* scale = (const float*)d_in[5];

  float* EQ  = (float*)d_ws;            // [1024][512]
  float* EKT = EQ + 1024 * 512;         // [4][512][256]

  float* ctx  = (float*)d_out;          // [4][256][512]
  float* attn = ctx + 4 * 256 * 512;    // [4][256][256]

  bah_proj<<<dim3(8, 16, 2), 256, 0, stream>>>(query, value, W1, W2, EQ, EKT);
  bah_attn<<<dim3(256), 512, 0, stream>>>(EQ, EKT, value, mask, scale, ctx, attn);
}

// Round 2
// 59.270 us; speedup vs baseline: 1.1353x; 1.1353x over previous
//
#include <hip/hip_runtime.h>

typedef float f4 __attribute__((ext_vector_type(4)));
typedef float f2 __attribute__((ext_vector_type(2)));

#define NEG_INF -1e9f

// ---------------------------------------------------------------------------
// Kernel 1: dual projection GEMM + exp epilogue (unchanged this round).
//   z=0: EQ[r][u]     = exp(2 * (query @ W1)[r][u])
//   z=1: EKT[b][u][v] = exp(2 * (value @ W2)[b*TV+v][u])  (transposed store)
// ---------------------------------------------------------------------------
__global__ __launch_bounds__(256) void bah_proj(
    const float* __restrict__ query, const float* __restrict__ value,
    const float* __restrict__ W1, const float* __restrict__ W2,
    float* __restrict__ EQ, float* __restrict__ EKT)
{
  const int z  = blockIdx.z;
  const int c0 = blockIdx.x * 64;
  const int r0 = blockIdx.y * 64;
  const float* __restrict__ X = z ? value : query;
  const float* __restrict__ W = z ? W2 : W1;

  __shared__ float As[32][68];
  __shared__ float Bs[32][68];

  const int tid = threadIdx.x;
  const int tx = tid & 15;
  const int ty = tid >> 4;

  float acc[4][4] = {};

  for (int kb = 0; kb < 512; kb += 32) {
#pragma unroll
    for (int t = 0; t < 2; ++t) {
      const int id  = t * 256 + tid;
      const int ar  = id >> 3;
      const int akc = (id & 7) * 4;
      f4 av = *reinterpret_cast<const f4*>(&X[(r0 + ar) * 512 + kb + akc]);
      As[akc + 0][ar] = av[0];
      As[akc + 1][ar] = av[1];
      As[akc + 2][ar] = av[2];
      As[akc + 3][ar] = av[3];
      const int bkk = id >> 4;
      const int bcc = (id & 15) * 4;
      f4 wv = *reinterpret_cast<const f4*>(&W[(kb + bkk) * 512 + c0 + bcc]);
      *reinterpret_cast<f4*>(&Bs[bkk][bcc]) = wv;
    }
    __syncthreads();
#pragma unroll
    for (int kk = 0; kk < 32; ++kk) {
      f4 a  = *reinterpret_cast<const f4*>(&As[kk][ty * 4]);
      f4 bb = *reinterpret_cast<const f4*>(&Bs[kk][tx * 4]);
#pragma unroll
      for (int i = 0; i < 4; ++i)
#pragma unroll
        for (int j = 0; j < 4; ++j)
          acc[i][j] = fmaf(a[i], bb[j], acc[i][j]);
    }
    __syncthreads();
  }

#pragma unroll
  for (int i = 0; i < 4; ++i) {
    const int r = r0 + ty * 4 + i;
#pragma unroll
    for (int j = 0; j < 4; ++j) {
      const int c = c0 + tx * 4 + j;
      const float e = __expf(2.0f * acc[i][j]);
      if (z == 0) EQ[r * 512 + c] = e;
      else        EKT[(r >> 8) * (512 * 256) + c * 256 + (r & 255)] = e;
    }
  }
}

// ---------------------------------------------------------------------------
// Kernel 2: fused scores + masked softmax + context.
// Grid: 256 blocks = (b, tq-group of 4). 1024 threads = 16 waves (4/SIMD).
// v = tid&255, u-quarter uq = tid>>8 (128 u's each).
// score = sumS - 2 * sum_u s_u * rcp(EQ*EK + 1)   [tanh identity]
// ---------------------------------------------------------------------------
__global__ __launch_bounds__(1024) void bah_attn(
    const float* __restrict__ EQ, const float* __restrict__ EKT,
    const float* __restrict__ value, const int* __restrict__ mask,
    const float* __restrict__ scale,
    float* __restrict__ ctx_out, float* __restrict__ attn_out)
{
  const int blk = blockIdx.x;
  const int b   = blk >> 6;
  const int tq0 = (blk & 63) * 4;
  const int bq  = b * 256 + tq0;

  const int tid = threadIdx.x;
  const int v   = tid & 255;
  const int uq  = tid >> 8;      // 0..3
  const int w   = tid >> 6;      // wave 0..15
  const int l   = tid & 63;

  __shared__ f4    eq4s[512];          // {row0..3} of EQ per u   (8 KB)
  __shared__ float ss[512];            // scale                   (2 KB)
  __shared__ float part[4][4][256];    // [uq][row][v]            (16 KB)
  __shared__ float wred[4][8];
  __shared__ float sumS_lds;
  __shared__ float atT[256][4];        // attn transposed         (4 KB)
  __shared__ float ctxp[4][4][512];    // [vchunk][row][d]        (32 KB)

  const float* __restrict__ ekb = EKT + b * (512 * 256);
  const float* __restrict__ eqb = EQ + bq * 512;

  // ---- stage EQ rows (packed f4) + scale into LDS ----
  if (tid < 512) {
    f4 e;
    e[0] = eqb[tid];
    e[1] = eqb[512 + tid];
    e[2] = eqb[1024 + tid];
    e[3] = eqb[1536 + tid];
    eq4s[tid] = e;
    ss[tid] = scale[tid];
  }
  __syncthreads();

  // sumS = sum(scale) by wave 0 (needed only at softmax time)
  if (w == 0) {
    float s = 0.f;
#pragma unroll
    for (int j = 0; j < 8; ++j) s += ss[l + 64 * j];
#pragma unroll
    for (int off = 32; off; off >>= 1) s += __shfl_xor(s, off);
    if (l == 0) sumS_lds = s;
  }

  // ---- main loop: 128 u's per thread ----
  float acc0 = 0.f, acc1 = 0.f, acc2 = 0.f, acc3 = 0.f;
  const float* __restrict__ pek = ekb + (uq * 128) * 256 + v;
  const int u0 = uq * 128;
#pragma unroll 4
  for (int uu = 0; uu < 128; ++uu) {
    const float ek = pek[uu * 256];          // coalesced, lane = v
    const f4    eq = eq4s[u0 + uu];          // LDS broadcast b128
    const float s  = ss[u0 + uu];            // LDS broadcast b32
    acc0 = fmaf(s, __builtin_amdgcn_rcpf(fmaf(eq[0], ek, 1.0f)), acc0);
    acc1 = fmaf(s, __builtin_amdgcn_rcpf(fmaf(eq[1], ek, 1.0f)), acc1);
    acc2 = fmaf(s, __builtin_amdgcn_rcpf(fmaf(eq[2], ek, 1.0f)), acc2);
    acc3 = fmaf(s, __builtin_amdgcn_rcpf(fmaf(eq[3], ek, 1.0f)), acc3);
  }
  part[uq][0][v] = acc0;
  part[uq][1][v] = acc1;
  part[uq][2][v] = acc2;
  part[uq][3][v] = acc3;
  __syncthreads();

  // ---- masked softmax over v (first 256 threads = waves 0..3) ----
  float sc[4], ex[4];
  if (tid < 256) {
    const float sumS = sumS_lds;
    const bool mok = (mask[b * 256 + v] != 0);
#pragma unroll
    for (int i = 0; i < 4; ++i) {
      const float p = (part[0][i][v] + part[1][i][v]) +
                      (part[2][i][v] + part[3][i][v]);
      sc[i] = mok ? (sumS - 2.0f * p) : NEG_INF;
      float m = sc[i];
#pragma unroll
      for (int off = 32; off; off >>= 1) m = fmaxf(m, __shfl_xor(m, off));
      if (l == 0) wred[i][w] = m;
    }
  }
  __syncthreads();
  if (tid < 256) {
#pragma unroll
    for (int i = 0; i < 4; ++i) {
      const float m = fmaxf(fmaxf(wred[i][0], wred[i][1]),
                            fmaxf(wred[i][2], wred[i][3]));
      float e = __expf(sc[i] - m);
      ex[i] = e;
      float sm = e;
#pragma unroll
      for (int off = 32; off; off >>= 1) sm += __shfl_xor(sm, off);
      if (l == 0) wred[i][4 + w] = sm;
    }
  }
  __syncthreads();
  if (tid < 256) {
#pragma unroll
    for (int i = 0; i < 4; ++i) {
      const float denom = (wred[i][4] + wred[i][5]) + (wred[i][6] + wred[i][7]);
      const float a = ex[i] * __builtin_amdgcn_rcpf(denom);
      atT[v][i] = a;
      attn_out[(bq + i) * 256 + v] = a;   // coalesced
    }
  }
  __syncthreads();

  // ---- context: 16 waves = 4 v-chunks x 4 d-quarters ----
  const int vc = w & 3;          // v-chunk of 64
  const int dq = w >> 2;         // d-quarter of 128
  const float* __restrict__ vb = value + b * (256 * 512);
  f2 c0v = {0.f, 0.f}, c1v = {0.f, 0.f}, c2v = {0.f, 0.f}, c3v = {0.f, 0.f};
  const int dbase = dq * 128 + l * 2;
  for (int v2 = 0; v2 < 64; ++v2) {
    const int vv = vc * 64 + v2;
    const f4 a4 = *reinterpret_cast<const f4*>(&atT[vv][0]);       // broadcast
    const f2 x  = *reinterpret_cast<const f2*>(&vb[vv * 512 + dbase]);
    c0v += a4[0] * x;
    c1v += a4[1] * x;
    c2v += a4[2] * x;
    c3v += a4[3] * x;
  }
  *reinterpret_cast<f2*>(&ctxp[vc][0][dbase]) = c0v;
  *reinterpret_cast<f2*>(&ctxp[vc][1][dbase]) = c1v;
  *reinterpret_cast<f2*>(&ctxp[vc][2][dbase]) = c2v;
  *reinterpret_cast<f2*>(&ctxp[vc][3][dbase]) = c3v;
  __syncthreads();

  // ---- final reduce over v-chunks + store ----
  if (tid < 512) {
    const int i  = tid >> 7;
    const int d4 = (tid & 127) * 4;
    const f4 s0 = *reinterpret_cast<const f4*>(&ctxp[0][i][d4]);
    const f4 s1 = *reinterpret_cast<const f4*>(&ctxp[1][i][d4]);
    const f4 s2 = *reinterpret_cast<const f4*>(&ctxp[2][i][d4]);
    const f4 s3 = *reinterpret_cast<const f4*>(&ctxp[3][i][d4]);
    const f4 r = (s0 + s1) + (s2 + s3);
    *reinterpret_cast<f4*>(&ctx_out[(bq + i) * 512 + d4]) = r;
  }
}

// ---------------------------------------------------------------------------
extern "C" void kernel_launch(void* const* d_in, const int* in_sizes, int n_in,
                              void* d_out, int out_size, void* d_ws, size_t ws_size,
                              hipStream_t stream) {
  const float* query = (const float*)d_in[0];
  const float* value = (const float*)d_in[1];
  const int*   mask  = (const int*)d_in[2];
  const float* W1    = (const float*)d_in[3];
  const float* W2    = (const float*)d_in[4];
  const float* scale = (const float*)d_in[5];

  float* EQ  = (float*)d_ws;            // [1024][512]
  float* EKT = EQ + 1024 * 512;         // [4][512][256]

  float* ctx  = (float*)d_out;          // [4][256][512]
  float* attn = ctx + 4 * 256 * 512;    // [4][256][256]

  bah_proj<<<dim3(8, 16, 2), 256, 0, stream>>>(query, value, W1, W2, EQ, EKT);
  bah_attn<<<dim3(256), 1024, 0, stream>>>(EQ, EKT, value, mask, scale, ctx, attn);
}

// Round 3
// 55.352 us; speedup vs baseline: 1.2157x; 1.0708x over previous
//
#include <hip/hip_runtime.h>

typedef float f4 __attribute__((ext_vector_type(4)));
typedef float f2 __attribute__((ext_vector_type(2)));
typedef short short8 __attribute__((ext_vector_type(8)));
typedef float f32x4 __attribute__((ext_vector_type(4)));

#define NEG_INF -1e9f

// ---------------------------------------------------------------------------
// bf16 split: x ~= hi + lo, both bf16 (RNE). 3-pass MFMA gives ~2^-16 accuracy.
// ---------------------------------------------------------------------------
__device__ inline void bsplit(float x, unsigned short& h, unsigned short& l) {
  union { float f; unsigned u; } a; a.f = x;
  unsigned rh = (a.u + 0x7fffu + ((a.u >> 16) & 1u)) >> 16;
  h = (unsigned short)rh;
  union { unsigned u; float f; } b; b.u = rh << 16;
  union { float f; unsigned u; } c; c.f = x - b.f;
  unsigned rl = (c.u + 0x7fffu + ((c.u >> 16) & 1u)) >> 16;
  l = (unsigned short)rl;
}

__device__ inline void gl_lds16(const void* g, void* l) {
  __builtin_amdgcn_global_load_lds(
      (const __attribute__((address_space(1))) unsigned int*)g,
      (__attribute__((address_space(3))) unsigned int*)l, 16, 0, 0);
}

// ---------------------------------------------------------------------------
// conv_a: pack X = {query rows 0..1023, value rows 0..1023} into
// A_perm[panel 32][kchunk 64][row 64][8] bf16 (hi & lo). panel = rows/64.
// ---------------------------------------------------------------------------
__global__ __launch_bounds__(256) void conv_a(
    const float* __restrict__ q, const float* __restrict__ v,
    unsigned short* __restrict__ Ahi, unsigned short* __restrict__ Alo)
{
  const int g = blockIdx.x * 256 + threadIdx.x;   // 131072 total
  const int row64 = g & 63;
  const int panel = (g >> 6) & 31;
  const int kc    = g >> 11;                       // 0..63
  const int rowg  = panel * 64 + row64;
  const float* src = (rowg < 1024) ? (q + (size_t)rowg * 512 + kc * 8)
                                   : (v + (size_t)(rowg - 1024) * 512 + kc * 8);
  f4 x0 = *reinterpret_cast<const f4*>(src);
  f4 x1 = *reinterpret_cast<const f4*>(src + 4);
  unsigned short h[8], l[8];
#pragma unroll
  for (int j = 0; j < 4; ++j) { bsplit(x0[j], h[j], l[j]); bsplit(x1[j], h[4+j], l[4+j]); }
  const size_t off = ((size_t)(panel * 64 + kc) * 64 + row64) * 8;
  short8 ph, pl;
#pragma unroll
  for (int j = 0; j < 8; ++j) { ph[j] = (short)h[j]; pl[j] = (short)l[j]; }
  *reinterpret_cast<short8*>(&Ahi[off]) = ph;
  *reinterpret_cast<short8*>(&Alo[off]) = pl;
}

// ---------------------------------------------------------------------------
// conv_w: W[z][512 k][512 n] -> Wt_perm[wpanel=z*8+np][kchunk 64][n 64][8] bf16
// (transpose via LDS tile).
// ---------------------------------------------------------------------------
__global__ __launch_bounds__(256) void conv_w(
    const float* __restrict__ W1, const float* __restrict__ W2,
    unsigned short* __restrict__ Whi, unsigned short* __restrict__ Wlo)
{
  const int kslab = blockIdx.x;      // 0..3   (128 k each)
  const int np    = blockIdx.y;      // 0..7   (64 n each)
  const int z     = blockIdx.z;      // 0..1
  const float* __restrict__ W = z ? W2 : W1;
  const int k0 = kslab * 128, n0 = np * 64;
  const int t = threadIdx.x;

  __shared__ float ldsW[128][64];
#pragma unroll
  for (int it = 0; it < 8; ++it) {
    const int idx = it * 256 + t;
    const int kr  = idx >> 4;
    const int nc4 = (idx & 15) * 4;
    *reinterpret_cast<f4*>(&ldsW[kr][nc4]) =
        *reinterpret_cast<const f4*>(&W[(size_t)(k0 + kr) * 512 + n0 + nc4]);
  }
  __syncthreads();

  const int wpanel = z * 8 + np;
  const int n = t & 63;
#pragma unroll
  for (int it = 0; it < 4; ++it) {
    const int kcl = it * 4 + (t >> 6);            // 0..15
    short8 ph, pl;
#pragma unroll
    for (int j = 0; j < 8; ++j) {
      unsigned short h, l;
      bsplit(ldsW[kcl * 8 + j][n], h, l);
      ph[j] = (short)h; pl[j] = (short)l;
    }
    const size_t off = ((size_t)(wpanel * 64 + kslab * 16 + kcl) * 64 + n) * 8;
    *reinterpret_cast<short8*>(&Whi[off]) = ph;
    *reinterpret_cast<short8*>(&Wlo[off]) = pl;
  }
}

// ---------------------------------------------------------------------------
// projmm: C = X @ W via 3-pass bf16-split MFMA (16x16x32), exp(2x) epilogue.
// Grid (8 nb, 16 mb, 2 z), 256 thr = 4 waves (2x2 of 32x32).
// z=0: EQ[row][col] = exp(2 (q@W1));  z=1: EKT[b][u][v] = exp(2 (v@W2)) transposed.
// LDS frag layout [kg 4][row 64][8 bf16] matches A_perm chunks exactly:
// staging = one contiguous global_load_lds(16B) per array per K-step.
// ---------------------------------------------------------------------------
__global__ __launch_bounds__(256) void projmm(
    const unsigned short* __restrict__ Ahi, const unsigned short* __restrict__ Alo,
    const unsigned short* __restrict__ Whi, const unsigned short* __restrict__ Wlo,
    float* __restrict__ EQ, float* __restrict__ EKT)
{
  const int nb = blockIdx.x, mb = blockIdx.y, z = blockIdx.z;
  const int t = threadIdx.x;
  const int l = t & 63;
  const int w = t >> 6;
  const int wr = w >> 1, wc = w & 1;

  __shared__ __align__(16) short Ast[2][2][2048];  // [buf][hi/lo][4kg*64row*8]
  __shared__ __align__(16) short Bst[2][2][2048];
  __shared__ float ldsT[64][67];

  const unsigned short* abase_h = Ahi + (size_t)(z * 16 + mb) * 32768;
  const unsigned short* abase_l = Alo + (size_t)(z * 16 + mb) * 32768;
  const unsigned short* wbase_h = Whi + (size_t)(z * 8 + nb) * 32768;
  const unsigned short* wbase_l = Wlo + (size_t)(z * 8 + nb) * 32768;

  const int ldst = (t >> 6) * 512;   // wave-uniform LDS dest base (shorts)
  const int gsrc = t * 8;            // per-lane global offset (shorts)

#define STAGE(buf, ks)                                                        \
  do {                                                                        \
    gl_lds16(abase_h + (ks) * 2048 + gsrc, &Ast[buf][0][ldst]);               \
    gl_lds16(abase_l + (ks) * 2048 + gsrc, &Ast[buf][1][ldst]);               \
    gl_lds16(wbase_h + (ks) * 2048 + gsrc, &Bst[buf][0][ldst]);               \
    gl_lds16(wbase_l + (ks) * 2048 + gsrc, &Bst[buf][1][ldst]);               \
  } while (0)

  f32x4 acc[2][2] = {};
  STAGE(0, 0);
  __syncthreads();

  int buf = 0;
  for (int ks = 0; ks < 16; ++ks) {
    if (ks < 15) STAGE(buf ^ 1, ks + 1);
    // fragment byte offsets: (l>>4)*1024 + (row|col)*16
    const int kgo = (l >> 4) * 1024;
    short8 ah[2], al[2], bh[2], bl[2];
#pragma unroll
    for (int i = 0; i < 2; ++i) {
      const int ro = (wr * 32 + i * 16 + (l & 15)) * 16;
      ah[i] = *reinterpret_cast<const short8*>((const char*)&Ast[buf][0][0] + kgo + ro);
      al[i] = *reinterpret_cast<const short8*>((const char*)&Ast[buf][1][0] + kgo + ro);
    }
#pragma unroll
    for (int j = 0; j < 2; ++j) {
      const int co = (wc * 32 + j * 16 + (l & 15)) * 16;
      bh[j] = *reinterpret_cast<const short8*>((const char*)&Bst[buf][0][0] + kgo + co);
      bl[j] = *reinterpret_cast<const short8*>((const char*)&Bst[buf][1][0] + kgo + co);
    }
#pragma unroll
    for (int i = 0; i < 2; ++i)
#pragma unroll
      for (int j = 0; j < 2; ++j) {
        acc[i][j] = __builtin_amdgcn_mfma_f32_16x16x32_bf16(ah[i], bh[j], acc[i][j], 0, 0, 0);
        acc[i][j] = __builtin_amdgcn_mfma_f32_16x16x32_bf16(ah[i], bl[j], acc[i][j], 0, 0, 0);
        acc[i][j] = __builtin_amdgcn_mfma_f32_16x16x32_bf16(al[i], bh[j], acc[i][j], 0, 0, 0);
      }
    __syncthreads();
    buf ^= 1;
  }

  if (z == 0) {
#pragma unroll
    for (int i = 0; i < 2; ++i)
#pragma unroll
      for (int j = 0; j < 2; ++j)
#pragma unroll
        for (int r = 0; r < 4; ++r) {
          const int row = mb * 64 + wr * 32 + i * 16 + (l >> 4) * 4 + r;
          const int col = nb * 64 + wc * 32 + j * 16 + (l & 15);
          EQ[(size_t)row * 512 + col] = __expf(2.0f * acc[i][j][r]);
        }
  } else {
#pragma unroll
    for (int i = 0; i < 2; ++i)
#pragma unroll
      for (int j = 0; j < 2; ++j)
#pragma unroll
        for (int r = 0; r < 4; ++r) {
          const int rl = wr * 32 + i * 16 + (l >> 4) * 4 + r;   // v-local
          const int cl = wc * 32 + j * 16 + (l & 15);           // u-local
          ldsT[rl][cl] = __expf(2.0f * acc[i][j][r]);
        }
    __syncthreads();
    const int b  = (mb * 64) >> 8;
    const int v0 = (mb * 64) & 255;
    const int vl = t & 63;
#pragma unroll
    for (int it = 0; it < 16; ++it) {
      const int ul = it * 4 + (t >> 6);
      EKT[(size_t)b * 131072 + (size_t)(nb * 64 + ul) * 256 + v0 + vl] = ldsT[vl][ul];
    }
  }
#undef STAGE
}

// ---------------------------------------------------------------------------
// bah_attn: fused scores + masked softmax + context.
// Grid 256 blocks (XCD-swizzled so each XCD serves one batch b), 1024 thr.
// Thread: v4 = tid&63 (4 v's), uq = tid>>6 (32 u's). 16 evals per
// {1 f4 global + 1 b128 LDS + 1 b32 LDS}.  score = sumS - 2*sum s*rcp(eq*ek+1).
// ---------------------------------------------------------------------------
__global__ __launch_bounds__(1024) void bah_attn(
    const float* __restrict__ EQ, const float* __restrict__ EKT,
    const float* __restrict__ value, const int* __restrict__ mask,
    const float* __restrict__ scale,
    float* __restrict__ ctx_out, float* __restrict__ attn_out)
{
  const int blk = blockIdx.x;
  // XCD-aware: blocks sharing batch b land on same XCD (default map = blk%8).
  const int b  = (blk & 7) >> 1;
  const int tg = (blk >> 3) + ((blk & 1) << 5);   // 0..63
  const int tq0 = tg * 4;
  const int bq  = b * 256 + tq0;

  const int tid = threadIdx.x;
  const int v4  = tid & 63;
  const int uq  = tid >> 6;      // 0..15 (also wave id)
  const int w   = tid >> 6;
  const int l   = tid & 63;

  __shared__ f4    eq4s[512];            // 8 KB
  __shared__ float ss[512];              // 2 KB
  __shared__ float part[16][4][256];     // 64 KB
  __shared__ float wred[4][8];
  __shared__ float sumS_lds;
  __shared__ float atT[256][4];          // 4 KB
  __shared__ float ctxp[4][4][512];      // 32 KB

  const float* __restrict__ ekb = EKT + (size_t)b * (512 * 256);
  const float* __restrict__ eqb = EQ + (size_t)bq * 512;

  if (tid < 512) {
    f4 e;
    e[0] = eqb[tid];
    e[1] = eqb[512 + tid];
    e[2] = eqb[1024 + tid];
    e[3] = eqb[1536 + tid];
    eq4s[tid] = e;
    ss[tid] = scale[tid];
  }
  __syncthreads();

  if (w == 0) {
    float s = 0.f;
#pragma unroll
    for (int j = 0; j < 8; ++j) s += ss[l + 64 * j];
#pragma unroll
    for (int off = 32; off; off >>= 1) s += __shfl_xor(s, off);
    if (l == 0) sumS_lds = s;
  }

  // ---- main loop: 32 u's x 4 v's x 4 rows per thread ----
  f4 acc[4] = {{0,0,0,0},{0,0,0,0},{0,0,0,0},{0,0,0,0}};
  const float* __restrict__ pek = ekb + (size_t)(uq * 32) * 256 + v4 * 4;
  const int u0 = uq * 32;
#pragma unroll 2
  for (int uu = 0; uu < 32; ++uu) {
    const f4 ek = *reinterpret_cast<const f4*>(pek + (size_t)uu * 256);
    const f4 eq = eq4s[u0 + uu];
    const float s = ss[u0 + uu];
#pragma unroll
    for (int i = 0; i < 4; ++i) {
      f4 r;
#pragma unroll
      for (int j = 0; j < 4; ++j)
        r[j] = __builtin_amdgcn_rcpf(fmaf(eq[i], ek[j], 1.0f));
#pragma unroll
      for (int j = 0; j < 4; ++j)
        acc[i][j] = fmaf(s, r[j], acc[i][j]);
    }
  }
#pragma unroll
  for (int i = 0; i < 4; ++i)
    *reinterpret_cast<f4*>(&part[uq][i][v4 * 4]) = acc[i];
  __syncthreads();

  // ---- reduce over uq + masked softmax (first 256 threads) ----
  float sc[4], ex[4];
  const int v = tid & 255;
  if (tid < 256) {
    const float sumS = sumS_lds;
    const bool mok = (mask[b * 256 + v] != 0);
#pragma unroll
    for (int i = 0; i < 4; ++i) {
      float p = 0.f;
#pragma unroll
      for (int u2 = 0; u2 < 16; ++u2) p += part[u2][i][v];
      sc[i] = mok ? (sumS - 2.0f * p) : NEG_INF;
      float m = sc[i];
#pragma unroll
      for (int off = 32; off; off >>= 1) m = fmaxf(m, __shfl_xor(m, off));
      if (l == 0) wred[i][w] = m;
    }
  }
  __syncthreads();
  if (tid < 256) {
#pragma unroll
    for (int i = 0; i < 4; ++i) {
      const float m = fmaxf(fmaxf(wred[i][0], wred[i][1]),
                            fmaxf(wred[i][2], wred[i][3]));
      float e = __expf(sc[i] - m);
      ex[i] = e;
      float sm = e;
#pragma unroll
      for (int off = 32; off; off >>= 1) sm += __shfl_xor(sm, off);
      if (l == 0) wred[i][4 + w] = sm;
    }
  }
  __syncthreads();
  if (tid < 256) {
#pragma unroll
    for (int i = 0; i < 4; ++i) {
      const float denom = (wred[i][4] + wred[i][5]) + (wred[i][6] + wred[i][7]);
      const float a = ex[i] * __builtin_amdgcn_rcpf(denom);
      atT[v][i] = a;
      attn_out[(size_t)(bq + i) * 256 + v] = a;
    }
  }
  __syncthreads();

  // ---- context: 16 waves = 4 v-chunks x 4 d-quarters ----
  const int vc = w & 3;
  const int dq = w >> 2;
  const float* __restrict__ vb = value + (size_t)b * (256 * 512);
  f2 c0v = {0.f, 0.f}, c1v = {0.f, 0.f}, c2v = {0.f, 0.f}, c3v = {0.f, 0.f};
  const int dbase = dq * 128 + l * 2;
  for (int v2 = 0; v2 < 64; ++v2) {
    const int vv = vc * 64 + v2;
    const f4 a4 = *reinterpret_cast<const f4*>(&atT[vv][0]);
    const f2 x  = *reinterpret_cast<const f2*>(&vb[(size_t)vv * 512 + dbase]);
    c0v += a4[0] * x;
    c1v += a4[1] * x;
    c2v += a4[2] * x;
    c3v += a4[3] * x;
  }
  *reinterpret_cast<f2*>(&ctxp[vc][0][dbase]) = c0v;
  *reinterpret_cast<f2*>(&ctxp[vc][1][dbase]) = c1v;
  *reinterpret_cast<f2*>(&ctxp[vc][2][dbase]) = c2v;
  *reinterpret_cast<f2*>(&ctxp[vc][3][dbase]) = c3v;
  __syncthreads();

  if (tid < 512) {
    const int i  = tid >> 7;
    const int d4 = (tid & 127) * 4;
    const f4 s0 = *reinterpret_cast<const f4*>(&ctxp[0][i][d4]);
    const f4 s1 = *reinterpret_cast<const f4*>(&ctxp[1][i][d4]);
    const f4 s2 = *reinterpret_cast<const f4*>(&ctxp[2][i][d4]);
    const f4 s3 = *reinterpret_cast<const f4*>(&ctxp[3][i][d4]);
    const f4 r = (s0 + s1) + (s2 + s3);
    *reinterpret_cast<f4*>(&ctx_out[(size_t)(bq + i) * 512 + d4]) = r;
  }
}

// ---------------------------------------------------------------------------
extern "C" void kernel_launch(void* const* d_in, const int* in_sizes, int n_in,
                              void* d_out, int out_size, void* d_ws, size_t ws_size,
                              hipStream_t stream) {
  const float* query = (const float*)d_in[0];
  const float* value = (const float*)d_in[1];
  const int*   mask  = (const int*)d_in[2];
  const float* W1    = (const float*)d_in[3];
  const float* W2    = (const float*)d_in[4];
  const float* scale = (const float*)d_in[5];

  char* ws = (char*)d_ws;
  float* EQ  = (float*)(ws);                         // 2 MB  [1024][512]
  float* EKT = (float*)(ws + (2u << 20));            // 2 MB  [4][512][256]
  unsigned short* Ahi = (unsigned short*)(ws + (4u << 20));   // 2 MB
  unsigned short* Alo = (unsigned short*)(ws + (6u << 20));   // 2 MB
  unsigned short* Whi = (unsigned short*)(ws + (8u << 20));   // 1 MB
  unsigned short* Wlo = (unsigned short*)(ws + (9u << 20));   // 1 MB

  float* ctx  = (float*)d_out;          // [4][256][512]
  float* attn = ctx + 4 * 256 * 512;    // [4][256][256]

  conv_a<<<dim3(512), 256, 0, stream>>>(query, value, Ahi, Alo);
  conv_w<<<dim3(4, 8, 2), 256, 0, stream>>>(W1, W2, Whi, Wlo);
  projmm<<<dim3(8, 16, 2), 256, 0, stream>>>(Ahi, Alo, Whi, Wlo, EQ, EKT);
  bah_attn<<<dim3(256), 1024, 0, stream>>>(EQ, EKT, value, mask, scale, ctx, attn);
}